// Round 3
// baseline (374.926 us; speedup 1.0000x reference)
//
#include <hip/hip_runtime.h>
#include <hip/hip_bf16.h>
#include <stdint.h>

#define B_ 4
#define T_ 512
#define H_ 32
#define N_ 64
#define D_ 2048
#define M_ (B_*T_)

typedef __attribute__((ext_vector_type(4))) float f32x4;
typedef __attribute__((ext_vector_type(8))) short short8;

// DPP butterfly add across 16-lane groups: pure VALU.
template <int CTRL>
__device__ __forceinline__ float dpp_add(float x) {
    int t = __builtin_amdgcn_mov_dpp(__float_as_int(x), CTRL, 0xF, 0xF, true);
    return x + __int_as_float(t);
}
__device__ __forceinline__ float bfly16(float x) {
    x = dpp_add<0xB1>(x);    // xor1
    x = dpp_add<0x4E>(x);    // xor2
    x = dpp_add<0x141>(x);   // xor4 row_half_mirror
    x = dpp_add<0x140>(x);   // xor8 row_mirror
    return x;
}

// ---------------------------------------------------------------------------
// Kernel 1: precompute+pack streams into pk[bh][t][6][64]
// (streams: r,k,v,dec,kk,bb).
// ---------------------------------------------------------------------------
__global__ __launch_bounds__(256) void prep(
    const float* __restrict__ r, const float* __restrict__ w,
    const float* __restrict__ k, const float* __restrict__ v,
    const float* __restrict__ iclr, float* __restrict__ pk) {
    int g = blockIdx.x * 4 + (threadIdx.x >> 6);   // (b,t,h) flat index
    int lane = threadIdx.x & 63;
    int b = g >> 14;             // / (T*H)
    int t = (g >> 5) & (T_ - 1); // / H % T
    int h = g & 31;              // % H
    size_t si = (size_t)g * 64 + lane;
    size_t di = (((size_t)(b * H_ + h) * T_) + t) * 384 + lane;  // stream 0 chan
    float rv = r[si], wv = w[si], kv = k[si], vv = v[si], av = iclr[si];
    float d = expf(-expf(wv));
    float ss = kv * kv;
#pragma unroll
    for (int m = 1; m < 64; m <<= 1) ss += __shfl_xor(ss, m, 64);
    float kkv = kv * rsqrtf(ss + 1e-12f);
    float bbv = kkv * (1.f / (1.f + expf(-av)));
    pk[di          ] = rv;
    pk[di + 1 * 64 ] = kv;
    pk[di + 2 * 64 ] = vv;
    pk[di + 3 * 64 ] = d;
    pk[di + 4 * 64 ] = kkv;
    pk[di + 5 * 64 ] = bbv;
}

// ---------------------------------------------------------------------------
// Kernel 2: WKV-7 scan. R7: NO LDS. R6 counters showed the LDS pipe was the
// bottleneck: per CU, 8 waves x (5 ds_read_b128 + ds_read_b32 + DMA writes)
// ~ 624 cyc/step vs the observed 567 cyc/step (VALUBusy pinned 46%, bank
// conflicts 0, HBM 11% -- classic hidden-pipe saturation). Fragments now load
// straight from pk into registers, software-pipelined depth 2 (use at t,
// issued at t-2). Intra-wave address duplication (4 row-groups read the same
// 256B) is free at the L1 line level; the 16 sibling blocks per (b,h) share
// an XCD (ids differ by 128 = 0 mod 8) so reads are L2-hits after the first
// toucher. Expected limiter moves to VALU issue (~260 cyc/step/CU).
// Blocks >= 2048: int32 -> bf16 weight dequant riding in the scan's shadow.
// ---------------------------------------------------------------------------
struct Frag {
    f32x4 R, Kk, Dd, Aa, Bb;
    float v;
};

__device__ __forceinline__ Frag ldfragG(const float* __restrict__ tb,
                                        int jg, int row) {
    Frag f;
    f.R  = *(const f32x4*)(tb + 0 * 64 + jg * 4);
    f.Kk = *(const f32x4*)(tb + 1 * 64 + jg * 4);
    f.v  = tb[2 * 64 + row];
    f.Dd = *(const f32x4*)(tb + 3 * 64 + jg * 4);
    f.Aa = *(const f32x4*)(tb + 4 * 64 + jg * 4);
    f.Bb = *(const f32x4*)(tb + 5 * 64 + jg * 4);
    return f;
}

__device__ __forceinline__ void wkv_step(float S[4], const Frag& f,
                                         __hip_bfloat16* __restrict__ y,
                                         int b, int h, int t, int jg, int row) {
    // sa = -(S_old . kk)
    float s01 = fmaf(S[1], f.Aa[1], S[0] * f.Aa[0]);
    float s23 = fmaf(S[3], f.Aa[3], S[2] * f.Aa[2]);
    const float sa = -bfly16(s01 + s23);

    // S = S*dec + sa*bb + v*k ;  y partial = S_new . r
    float t0 = fmaf(sa, f.Bb[0], f.v * f.Kk[0]);
    S[0] = fmaf(S[0], f.Dd[0], t0);
    float t1 = fmaf(sa, f.Bb[1], f.v * f.Kk[1]);
    S[1] = fmaf(S[1], f.Dd[1], t1);
    float y01 = fmaf(S[1], f.R[1], S[0] * f.R[0]);
    float t2 = fmaf(sa, f.Bb[2], f.v * f.Kk[2]);
    S[2] = fmaf(S[2], f.Dd[2], t2);
    float t3 = fmaf(sa, f.Bb[3], f.v * f.Kk[3]);
    S[3] = fmaf(S[3], f.Dd[3], t3);
    float y23 = fmaf(S[3], f.R[3], S[2] * f.R[2]);
    float ys = bfly16(y01 + y23);
    if (jg == 0)
        y[((size_t)b * T_ + t) * D_ + h * 64 + row] = __float2bfloat16(ys);
}

__global__ __launch_bounds__(64, 2) void wkv_scan(
    const float* __restrict__ pk, __hip_bfloat16* __restrict__ y,
    const int* __restrict__ q, __hip_bfloat16* __restrict__ o) {
    if (blockIdx.x >= 2048) {      // ---- weight dequant part ----
        int i = ((blockIdx.x - 2048) * 64 + (int)threadIdx.x) * 4;
        int4 qi = *(const int4*)(q + i);
        __hip_bfloat16 t[4];
        t[0] = __float2bfloat16((float)qi.x);
        t[1] = __float2bfloat16((float)qi.y);
        t[2] = __float2bfloat16((float)qi.z);
        t[3] = __float2bfloat16((float)qi.w);
        *(uint2*)(o + i) = *(uint2*)t;
        return;
    }
    const int bh = blockIdx.x & 127;
    const int wv = blockIdx.x >> 7;
    const int b = bh >> 5, h = bh & 31;
    const int lane = threadIdx.x;
    const int jg = lane & 15;
    const int rl = lane >> 4;
    const int row = wv * 4 + rl;

    const float* src = pk + (size_t)bh * T_ * 384;

    // software pipeline, depth 2: frag for step t is issued at t-2
    Frag fa = ldfragG(src, jg, row);
    Frag fb = ldfragG(src + 384, jg, row);
    float S[4] = {0.f, 0.f, 0.f, 0.f};

    for (int t = 0; t < T_; t += 2) {
        int t2 = t + 2; if (t2 > T_ - 1) t2 = T_ - 1;   // tail re-read: unused
        int t3 = t + 3; if (t3 > T_ - 1) t3 = T_ - 1;
        Frag fc = ldfragG(src + (size_t)t2 * 384, jg, row);
        wkv_step(S, fa, y, b, h, t, jg, row);
        Frag fd = ldfragG(src + (size_t)t3 * 384, jg, row);
        wkv_step(S, fb, y, b, h, t + 1, jg, row);
        fa = fc;
        fb = fd;
    }
}

// ---------------------------------------------------------------------------
// Kernel 3: C[m,o] = scale[o] * sum_d Y[m,d] * Wq[o,d]  (B^T GEMM)
// 128x64 tile, BK=64, 4 waves (2x2 over 64x32 sub-tiles).
// 512 blocks = 2/CU so the co-resident block covers barrier drains.
// ---------------------------------------------------------------------------
__device__ __forceinline__ void gload_lds16(const __hip_bfloat16* g, ushort* l) {
    __builtin_amdgcn_global_load_lds(
        (const __attribute__((address_space(1))) unsigned int*)g,
        (__attribute__((address_space(3))) unsigned int*)l, 16, 0, 0);
}

__global__ __launch_bounds__(256, 2) void gemm_bt(
    const __hip_bfloat16* __restrict__ A,   // [M, K]
    const __hip_bfloat16* __restrict__ Bq,  // [N, K]
    const float* __restrict__ scale,        // [N]
    float* __restrict__ C) {                // [M, N]
    const int K = D_;
    __shared__ __align__(16) ushort As[128 * 64];   // 16 KB
    __shared__ __align__(16) ushort Bs[64 * 64];    //  8 KB

    const int tid = threadIdx.x;
    const int lane = tid & 63;
    const int wave = tid >> 6;
    const int wr = wave >> 1, wc = wave & 1;
    const int m0 = blockIdx.x * 128;
    const int n0 = blockIdx.y * 64;

    const int srow8 = lane >> 3;
    const int scol8 = (lane & 7) * 8;
    const int ml = lane & 15;
    const int kq = (lane >> 4) * 8;

    f32x4 acc[4][2] = {};

    for (int k0 = 0; k0 < K; k0 += 64) {
#pragma unroll
        for (int c = 0; c < 4; ++c) {
            int ra = wave * 32 + c * 8;
            gload_lds16(A + (size_t)(m0 + ra + srow8) * K + k0 + scol8,
                        &As[ra * 64]);
        }
#pragma unroll
        for (int c = 0; c < 2; ++c) {
            int rb = wave * 16 + c * 8;
            gload_lds16(Bq + (size_t)(n0 + rb + srow8) * K + k0 + scol8,
                        &Bs[rb * 64]);
        }
        __syncthreads();
#pragma unroll
        for (int ks = 0; ks < 2; ++ks) {
            short8 af[4], bf[2];
#pragma unroll
            for (int tm = 0; tm < 4; ++tm)
                af[tm] = *(const short8*)(&As[(wr * 64 + tm * 16 + ml) * 64 + ks * 32 + kq]);
#pragma unroll
            for (int tn = 0; tn < 2; ++tn)
                bf[tn] = *(const short8*)(&Bs[(wc * 32 + tn * 16 + ml) * 64 + ks * 32 + kq]);
#pragma unroll
            for (int tm = 0; tm < 4; ++tm)
#pragma unroll
                for (int tn = 0; tn < 2; ++tn)
                    acc[tm][tn] = __builtin_amdgcn_mfma_f32_16x16x32_bf16(
                        af[tm], bf[tn], acc[tm][tn], 0, 0, 0);
        }
        __syncthreads();
    }

#pragma unroll
    for (int tn = 0; tn < 2; ++tn) {
        int gn = n0 + wc * 32 + tn * 16 + ml;
        float sc = scale[gn];
#pragma unroll
        for (int tm = 0; tm < 4; ++tm) {
            int gm = m0 + wr * 64 + tm * 16 + (lane >> 4) * 4;
#pragma unroll
            for (int rg = 0; rg < 4; ++rg)
                C[(size_t)(gm + rg) * D_ + gn] = acc[tm][tn][rg] * sc;
        }
    }
}

// ---------------------------------------------------------------------------
extern "C" void kernel_launch(void* const* d_in, const int* in_sizes, int n_in,
                              void* d_out, int out_size, void* d_ws, size_t ws_size,
                              hipStream_t stream) {
    (void)in_sizes; (void)n_in; (void)out_size; (void)ws_size;
    const float* r  = (const float*)d_in[0];
    const float* w  = (const float*)d_in[1];
    const float* k  = (const float*)d_in[2];
    const float* v  = (const float*)d_in[3];
    const float* ic = (const float*)d_in[4];
    const int*   wq = (const int*)d_in[5];
    const float* sc = (const float*)d_in[6];
    float* out = (float*)d_out;

    // ws: yb 8.4MB | wb 8.4MB | pk (packed streams) 100.7MB  (~118 MB total)
    char* p = (char*)d_ws;
    __hip_bfloat16* yb = (__hip_bfloat16*)p;  p += (size_t)M_ * D_ * 2;
    __hip_bfloat16* wb = (__hip_bfloat16*)p;  p += (size_t)D_ * D_ * 2;
    float* pk = (float*)p;

    prep    <<<dim3(16384), dim3(256), 0, stream>>>(r, w, k, v, ic, pk);
    wkv_scan<<<dim3(2048 + 16384), dim3(64), 0, stream>>>(pk, yb, wq, wb);
    gemm_bt <<<dim3(M_ / 128, D_ / 64), dim3(256), 0, stream>>>(yb, wb, sc, out);
}

// Round 4
// 325.969 us; speedup vs baseline: 1.1502x; 1.1502x over previous
//
#include <hip/hip_runtime.h>
#include <hip/hip_bf16.h>
#include <stdint.h>

#define B_ 4
#define T_ 512
#define H_ 32
#define N_ 64
#define D_ 2048
#define M_ (B_*T_)

typedef __attribute__((ext_vector_type(4))) float f32x4;
typedef __attribute__((ext_vector_type(8))) short short8;

// DPP butterfly add across 16-lane groups: pure VALU.
template <int CTRL>
__device__ __forceinline__ float dpp_add(float x) {
    int t = __builtin_amdgcn_mov_dpp(__float_as_int(x), CTRL, 0xF, 0xF, true);
    return x + __int_as_float(t);
}
__device__ __forceinline__ float bfly16(float x) {
    x = dpp_add<0xB1>(x);    // xor1
    x = dpp_add<0x4E>(x);    // xor2
    x = dpp_add<0x141>(x);   // xor4 row_half_mirror
    x = dpp_add<0x140>(x);   // xor8 row_mirror
    return x;
}

__device__ __forceinline__ void gld16(const void* g, void* l) {
    __builtin_amdgcn_global_load_lds(
        (const __attribute__((address_space(1))) unsigned int*)g,
        (__attribute__((address_space(3))) unsigned int*)l, 16, 0, 0);
}

__device__ __forceinline__ ushort f2bf(float x) {   // RNE f32->bf16
    uint u = __float_as_uint(x);
    return (ushort)((u + 0x7fffu + ((u >> 16) & 1u)) >> 16);
}

// ---------------------------------------------------------------------------
// Kernel 1: precompute+pack streams, 1024B per (b,h,t):
//   [RK: 64 x {bf16 r, bf16 k} dwords = 256B][AB: {bf16 kk, bf16 bb} = 256B]
//   [D: 64 f32 = 256B][V: 64 f32 = 256B]
// bf16 for the 4 linear (non-compounding) streams halves LDS reads in the
// scan (R8: LDS pipe was the saturated resource, 576 cyc/step/CU demand vs
// 567 observed). Decay stays f32 (512-step compounding), v stays f32.
// ---------------------------------------------------------------------------
__global__ __launch_bounds__(256) void prep(
    const float* __restrict__ r, const float* __restrict__ w,
    const float* __restrict__ k, const float* __restrict__ v,
    const float* __restrict__ iclr, char* __restrict__ pk) {
    int g = blockIdx.x * 4 + (threadIdx.x >> 6);   // (b,t,h) flat index
    int lane = threadIdx.x & 63;
    int b = g >> 14;             // / (T*H)
    int t = (g >> 5) & (T_ - 1); // / H % T
    int h = g & 31;              // % H
    size_t si = (size_t)g * 64 + lane;
    char* dst = pk + ((size_t)(b * H_ + h) * T_ + t) * 1024;
    float rv = r[si], wv = w[si], kv = k[si], vv = v[si], av = iclr[si];
    float d = expf(-expf(wv));
    float ss = kv * kv;
#pragma unroll
    for (int m = 1; m < 64; m <<= 1) ss += __shfl_xor(ss, m, 64);
    float kkv = kv * rsqrtf(ss + 1e-12f);
    float bbv = kkv * (1.f / (1.f + expf(-av)));
    uint rk = (uint)f2bf(rv) | ((uint)f2bf(kv) << 16);
    uint ab = (uint)f2bf(kkv) | ((uint)f2bf(bbv) << 16);
    *(uint*)(dst + lane * 4)        = rk;
    *(uint*)(dst + 256 + lane * 4)  = ab;
    *(float*)(dst + 512 + lane * 4) = d;
    *(float*)(dst + 768 + lane * 4) = vv;
}

// ---------------------------------------------------------------------------
// Kernel 2: WKV-7 scan. R6 skeleton (LDS ring + global_load_lds + counted
// vmcnt; 121us) with packed streams: per step per lane 2x ds_read_b128
// (RK, AB bf16 pairs) + 1x ds_read_b128 (D f32) + 1x ds_read_b32 (v)
// = 4 LDS reads vs 6. Per-CU LDS demand ~400 cyc/step (was ~576 = wall).
// Ring: 2 superslots x 4 steps x 1024B = 8KB. Refill = 4 width-16 DMAs
// per 4 steps.
// vmcnt ledger: per group 4 DMA + 4 y-stores. At top of group g (steady),
// queue oldest->newest = [4 DMA (data g)][4 stores g-1][4 DMA (data g+1)]
// -> vmcnt(8) drains data-g DMAs. g==0: prologue [4 s0][4 s1] -> vmcnt(4).
// Blocks >= 2048: int32 -> bf16 weight dequant riding in the scan's shadow.
// ---------------------------------------------------------------------------
__global__ __launch_bounds__(64, 2) void wkv_scan(
    const char* __restrict__ pk, __hip_bfloat16* __restrict__ y,
    const int* __restrict__ q, __hip_bfloat16* __restrict__ o) {
    if (blockIdx.x >= 2048) {      // ---- weight dequant part ----
        int i = ((blockIdx.x - 2048) * 64 + (int)threadIdx.x) * 4;
        int4 qi = *(const int4*)(q + i);
        __hip_bfloat16 t[4];
        t[0] = __float2bfloat16((float)qi.x);
        t[1] = __float2bfloat16((float)qi.y);
        t[2] = __float2bfloat16((float)qi.z);
        t[3] = __float2bfloat16((float)qi.w);
        *(uint2*)(o + i) = *(uint2*)t;
        return;
    }
    const int bh = blockIdx.x & 127;
    const int wv = blockIdx.x >> 7;
    const int b = bh >> 5, h = bh & 31;
    const int lane = threadIdx.x;
    const int jg = lane & 15;
    const int rl = lane >> 4;
    const int row = wv * 4 + rl;

    __shared__ __align__(16) char ring[2 * 4096];   // 8 KB

    const char* src = pk + (size_t)bh * T_ * 1024;

    // prologue: fill both superslots (8 DMAs outstanding)
#pragma unroll
    for (int gg = 0; gg < 2; ++gg)
#pragma unroll
        for (int c = 0; c < 4; ++c)
            gld16(src + (size_t)gg * 4096 + c * 1024 + lane * 16,
                  &ring[gg * 4096 + c * 1024 + lane * 16]);

    float S[4] = {0.f, 0.f, 0.f, 0.f};

    for (int g = 0; g < T_ / 4; ++g) {
        if (g == 0) { asm volatile("s_waitcnt vmcnt(4)" ::: "memory"); }
        else        { asm volatile("s_waitcnt vmcnt(8)" ::: "memory"); }
        const char* rb0 = &ring[(g & 1) * 4096];

#pragma unroll
        for (int i = 0; i < 4; ++i) {
            const int t = g * 4 + i;
            const char* rb = rb0 + i * 1024;

            uint4 rk  = *(const uint4*)(rb + jg * 16);
            uint4 ab  = *(const uint4*)(rb + 256 + jg * 16);
            f32x4 Dc  = *(const f32x4*)(rb + 512 + jg * 16);
            float vcv = *(const float*)(rb + 768 + row * 4);

            float R[4], K[4], A[4], Bv[4];
            uint rr[4] = {rk.x, rk.y, rk.z, rk.w};
            uint aa[4] = {ab.x, ab.y, ab.z, ab.w};
#pragma unroll
            for (int j = 0; j < 4; ++j) {
                R[j]  = __uint_as_float(rr[j] << 16);
                K[j]  = __uint_as_float(rr[j] & 0xffff0000u);
                A[j]  = __uint_as_float(aa[j] << 16);
                Bv[j] = __uint_as_float(aa[j] & 0xffff0000u);
            }

            // sa = -(S_old . kk)
            float s01 = fmaf(S[1], A[1], S[0] * A[0]);
            float s23 = fmaf(S[3], A[3], S[2] * A[2]);
            const float sa = -bfly16(s01 + s23);

            // S = S*dec + sa*bb + v*k ;  y partial = S_new . r
            float t0 = fmaf(sa, Bv[0], vcv * K[0]);
            S[0] = fmaf(S[0], Dc[0], t0);
            float t1 = fmaf(sa, Bv[1], vcv * K[1]);
            S[1] = fmaf(S[1], Dc[1], t1);
            float y01 = fmaf(S[1], R[1], S[0] * R[0]);
            float t2 = fmaf(sa, Bv[2], vcv * K[2]);
            S[2] = fmaf(S[2], Dc[2], t2);
            float t3 = fmaf(sa, Bv[3], vcv * K[3]);
            S[3] = fmaf(S[3], Dc[3], t3);
            float y23 = fmaf(S[3], R[3], S[2] * R[2]);
            float ys = bfly16(y01 + y23);
            if (jg == 0)
                y[((size_t)b * T_ + t) * D_ + h * 64 + row] =
                    __float2bfloat16(ys);
        }

        // refill this slot with group g+2 (clamped tail re-reads: harmless)
        asm volatile("" ::: "memory");
        int gp = g + 2; if (gp > T_ / 4 - 1) gp = T_ / 4 - 1;
        const char* g0 = src + (size_t)gp * 4096 + lane * 16;
        char* l0 = &ring[(g & 1) * 4096];
#pragma unroll
        for (int c = 0; c < 4; ++c)
            gld16(g0 + c * 1024, l0 + c * 1024 + lane * 16);
    }
}

// ---------------------------------------------------------------------------
// Kernel 3: C[m,o] = scale[o] * sum_d Y[m,d] * Wq[o,d]  (B^T GEMM)
// 128x64 tile, BK=64, 4 waves (2x2 over 64x32 sub-tiles).
// 512 blocks = 2/CU so the co-resident block covers barrier drains.
// ---------------------------------------------------------------------------
__device__ __forceinline__ void gload_lds16(const __hip_bfloat16* g, ushort* l) {
    __builtin_amdgcn_global_load_lds(
        (const __attribute__((address_space(1))) unsigned int*)g,
        (__attribute__((address_space(3))) unsigned int*)l, 16, 0, 0);
}

__global__ __launch_bounds__(256, 2) void gemm_bt(
    const __hip_bfloat16* __restrict__ A,   // [M, K]
    const __hip_bfloat16* __restrict__ Bq,  // [N, K]
    const float* __restrict__ scale,        // [N]
    float* __restrict__ C) {                // [M, N]
    const int K = D_;
    __shared__ __align__(16) ushort As[128 * 64];   // 16 KB
    __shared__ __align__(16) ushort Bs[64 * 64];    //  8 KB

    const int tid = threadIdx.x;
    const int lane = tid & 63;
    const int wave = tid >> 6;
    const int wr = wave >> 1, wc = wave & 1;
    const int m0 = blockIdx.x * 128;
    const int n0 = blockIdx.y * 64;

    const int srow8 = lane >> 3;
    const int scol8 = (lane & 7) * 8;
    const int ml = lane & 15;
    const int kq = (lane >> 4) * 8;

    f32x4 acc[4][2] = {};

    for (int k0 = 0; k0 < K; k0 += 64) {
#pragma unroll
        for (int c = 0; c < 4; ++c) {
            int ra = wave * 32 + c * 8;
            gload_lds16(A + (size_t)(m0 + ra + srow8) * K + k0 + scol8,
                        &As[ra * 64]);
        }
#pragma unroll
        for (int c = 0; c < 2; ++c) {
            int rb = wave * 16 + c * 8;
            gload_lds16(Bq + (size_t)(n0 + rb + srow8) * K + k0 + scol8,
                        &Bs[rb * 64]);
        }
        __syncthreads();
#pragma unroll
        for (int ks = 0; ks < 2; ++ks) {
            short8 af[4], bf[2];
#pragma unroll
            for (int tm = 0; tm < 4; ++tm)
                af[tm] = *(const short8*)(&As[(wr * 64 + tm * 16 + ml) * 64 + ks * 32 + kq]);
#pragma unroll
            for (int tn = 0; tn < 2; ++tn)
                bf[tn] = *(const short8*)(&Bs[(wc * 32 + tn * 16 + ml) * 64 + ks * 32 + kq]);
#pragma unroll
            for (int tm = 0; tm < 4; ++tm)
#pragma unroll
                for (int tn = 0; tn < 2; ++tn)
                    acc[tm][tn] = __builtin_amdgcn_mfma_f32_16x16x32_bf16(
                        af[tm], bf[tn], acc[tm][tn], 0, 0, 0);
        }
        __syncthreads();
    }

#pragma unroll
    for (int tn = 0; tn < 2; ++tn) {
        int gn = n0 + wc * 32 + tn * 16 + ml;
        float sc = scale[gn];
#pragma unroll
        for (int tm = 0; tm < 4; ++tm) {
            int gm = m0 + wr * 64 + tm * 16 + (lane >> 4) * 4;
#pragma unroll
            for (int rg = 0; rg < 4; ++rg)
                C[(size_t)(gm + rg) * D_ + gn] = acc[tm][tn][rg] * sc;
        }
    }
}

// ---------------------------------------------------------------------------
extern "C" void kernel_launch(void* const* d_in, const int* in_sizes, int n_in,
                              void* d_out, int out_size, void* d_ws, size_t ws_size,
                              hipStream_t stream) {
    (void)in_sizes; (void)n_in; (void)out_size; (void)ws_size;
    const float* r  = (const float*)d_in[0];
    const float* w  = (const float*)d_in[1];
    const float* k  = (const float*)d_in[2];
    const float* v  = (const float*)d_in[3];
    const float* ic = (const float*)d_in[4];
    const int*   wq = (const int*)d_in[5];
    const float* sc = (const float*)d_in[6];
    float* out = (float*)d_out;

    // ws: yb 8.4MB | wb 8.4MB | pk (packed streams, 1KB/step) 67MB
    char* p = (char*)d_ws;
    __hip_bfloat16* yb = (__hip_bfloat16*)p;  p += (size_t)M_ * D_ * 2;
    __hip_bfloat16* wb = (__hip_bfloat16*)p;  p += (size_t)D_ * D_ * 2;
    char* pk = p;

    prep    <<<dim3(16384), dim3(256), 0, stream>>>(r, w, k, v, ic, pk);
    wkv_scan<<<dim3(2048 + 16384), dim3(64), 0, stream>>>(pk, yb, wq, wb);
    gemm_bt <<<dim3(M_ / 128, D_ / 64), dim3(256), 0, stream>>>(yb, wb, sc, out);
}

// Round 5
// 299.250 us; speedup vs baseline: 1.2529x; 1.0893x over previous
//
#include <hip/hip_runtime.h>
#include <hip/hip_bf16.h>
#include <stdint.h>

#define B_ 4
#define T_ 512
#define H_ 32
#define N_ 64
#define D_ 2048
#define M_ (B_*T_)

typedef __attribute__((ext_vector_type(4))) float f32x4;
typedef __attribute__((ext_vector_type(8))) short short8;

// DPP butterfly add across 16-lane groups: pure VALU.
template <int CTRL>
__device__ __forceinline__ float dpp_add(float x) {
    int t = __builtin_amdgcn_mov_dpp(__float_as_int(x), CTRL, 0xF, 0xF, true);
    return x + __int_as_float(t);
}
__device__ __forceinline__ float bfly16(float x) {
    x = dpp_add<0xB1>(x);    // xor1
    x = dpp_add<0x4E>(x);    // xor2
    x = dpp_add<0x141>(x);   // xor4 row_half_mirror
    x = dpp_add<0x140>(x);   // xor8 row_mirror
    return x;
}

__device__ __forceinline__ void gld16(const float* g, float* l) {
    __builtin_amdgcn_global_load_lds(
        (const __attribute__((address_space(1))) unsigned int*)g,
        (__attribute__((address_space(3))) unsigned int*)l, 16, 0, 0);
}

// ---------------------------------------------------------------------------
// Kernel 1: precompute+pack streams into pk[bh][t][6][64] f32
// (streams: r,k,v,dec,kk,bb) -- exact R2 layout (proven 121us skeleton).
// ---------------------------------------------------------------------------
__global__ __launch_bounds__(256) void prep(
    const float* __restrict__ r, const float* __restrict__ w,
    const float* __restrict__ k, const float* __restrict__ v,
    const float* __restrict__ iclr, float* __restrict__ pk) {
    int g = blockIdx.x * 4 + (threadIdx.x >> 6);   // (b,t,h) flat index
    int lane = threadIdx.x & 63;
    int b = g >> 14;             // / (T*H)
    int t = (g >> 5) & (T_ - 1); // / H % T
    int h = g & 31;              // % H
    size_t si = (size_t)g * 64 + lane;
    size_t di = (((size_t)(b * H_ + h) * T_) + t) * 384 + lane;  // stream 0 chan
    float rv = r[si], wv = w[si], kv = k[si], vv = v[si], av = iclr[si];
    float d = expf(-expf(wv));
    float ss = kv * kv;
#pragma unroll
    for (int m = 1; m < 64; m <<= 1) ss += __shfl_xor(ss, m, 64);
    float kkv = kv * rsqrtf(ss + 1e-12f);
    float bbv = kkv * (1.f / (1.f + expf(-av)));
    pk[di          ] = rv;
    pk[di + 1 * 64 ] = kv;
    pk[di + 2 * 64 ] = vv;
    pk[di + 3 * 64 ] = d;
    pk[di + 4 * 64 ] = kkv;
    pk[di + 5 * 64 ] = bbv;
}

// ---------------------------------------------------------------------------
// Kernel 2: WKV-7 scan. R10: inline-asm double-buffered ds_reads.
// Four rounds of evidence: hipcc sinks C-level LDS loads to just-before-use
// (VGPR stuck 40-52), so each step pays ~120cyc ds_read latency in the
// serial chain; with only 2 waves/SIMD that latency is unhidden -> 567
// cyc/step wall. Fix: issue step s+1's 6 ds_reads via volatile asm into a
// second named fragment set BEFORE computing step s; a data-tied
// s_waitcnt lgkmcnt(6) ("+v" on the fragment regs, rule-18-safe) retires
// exactly the older set.
// lgkm ledger: reads alternate FA/FB, 6 per issue; at any tie exactly 12
// are outstanding -> lgkmcnt(6) retires the older set.
// vmcnt ledger: refill = 6 DMAs at odd pairs (once per group); gate before
// issuing reads into group g+1: outstanding = [<=2 old stores][6 DMA
// data g+1][3 stores this group] -> vmcnt(3) guarantees DMAs landed.
// Refill of slot g&1 sits after the tie that retires that slot's last
// reads (step 4g+3), so no DMA-write/ds_read race.
// Blocks >= 2048: int32 -> bf16 weight dequant riding in the scan's shadow.
// ---------------------------------------------------------------------------
struct Frag {
    f32x4 R, Kk, Dd, Aa, Bb;
    float v;
};

#define ISSUE_FRAG(F, a0, a1)                                   \
    asm volatile(                                               \
        "ds_read_b128 %0, %6 offset:1024\n\t"                   \
        "ds_read_b128 %1, %6 offset:1280\n\t"                   \
        "ds_read_b128 %2, %6 offset:0\n\t"                      \
        "ds_read_b128 %3, %6 offset:256\n\t"                    \
        "ds_read_b128 %4, %6 offset:768\n\t"                    \
        "ds_read_b32  %5, %7"                                   \
        : "+v"(F.Aa), "+v"(F.Bb), "+v"(F.R), "+v"(F.Kk),        \
          "+v"(F.Dd), "+v"(F.v)                                 \
        : "v"(a0), "v"(a1))

#define TIE_FRAG(F)                                             \
    asm volatile("s_waitcnt lgkmcnt(6)"                         \
        : "+v"(F.Aa), "+v"(F.Bb), "+v"(F.R), "+v"(F.Kk),        \
          "+v"(F.Dd), "+v"(F.v) :: "memory")

__device__ __forceinline__ void step_c(float S[4], const Frag& F,
                                       __hip_bfloat16* __restrict__ y,
                                       int b, int h, int t, int jg, int row) {
    // sa = -(S_old . kk)
    float s01 = fmaf(S[1], F.Aa[1], S[0] * F.Aa[0]);
    float s23 = fmaf(S[3], F.Aa[3], S[2] * F.Aa[2]);
    const float sa = -bfly16(s01 + s23);

    // S = S*dec + sa*bb + v*k ;  y partial = S_new . r
    float t0 = fmaf(sa, F.Bb[0], F.v * F.Kk[0]);
    S[0] = fmaf(S[0], F.Dd[0], t0);
    float t1 = fmaf(sa, F.Bb[1], F.v * F.Kk[1]);
    S[1] = fmaf(S[1], F.Dd[1], t1);
    float y01 = fmaf(S[1], F.R[1], S[0] * F.R[0]);
    float t2 = fmaf(sa, F.Bb[2], F.v * F.Kk[2]);
    S[2] = fmaf(S[2], F.Dd[2], t2);
    float t3 = fmaf(sa, F.Bb[3], F.v * F.Kk[3]);
    S[3] = fmaf(S[3], F.Dd[3], t3);
    float y23 = fmaf(S[3], F.R[3], S[2] * F.R[2]);
    float ys = bfly16(y01 + y23);
    if (jg == 0)
        y[((size_t)b * T_ + t) * D_ + h * 64 + row] = __float2bfloat16(ys);
}

__global__ __launch_bounds__(64, 2) void wkv_scan(
    const float* __restrict__ pk, __hip_bfloat16* __restrict__ y,
    const int* __restrict__ q, __hip_bfloat16* __restrict__ o) {
    if (blockIdx.x >= 2048) {      // ---- weight dequant part ----
        int i = ((blockIdx.x - 2048) * 64 + (int)threadIdx.x) * 4;
        int4 qi = *(const int4*)(q + i);
        __hip_bfloat16 t[4];
        t[0] = __float2bfloat16((float)qi.x);
        t[1] = __float2bfloat16((float)qi.y);
        t[2] = __float2bfloat16((float)qi.z);
        t[3] = __float2bfloat16((float)qi.w);
        *(uint2*)(o + i) = *(uint2*)t;
        return;
    }
    const int bh = blockIdx.x & 127;
    const int wv = blockIdx.x >> 7;
    const int b = bh >> 5, h = bh & 31;
    const int lane = threadIdx.x;
    const int jg = lane & 15;
    const int rl = lane >> 4;
    const int row = wv * 4 + rl;

    __shared__ __align__(16) float ring[2 * 1536];   // 12 KB

    const float* src = pk + (size_t)bh * T_ * 384;

    // prologue: fill both superslots (12 DMAs outstanding)
#pragma unroll
    for (int gg = 0; gg < 2; ++gg) {
        const float* g0 = src + (size_t)gg * 1536 + lane * 4;
        float* l0 = &ring[gg * 1536];
#pragma unroll
        for (int c = 0; c < 6; ++c)
            gld16(g0 + c * 256, l0 + c * 256);
    }

    // 32-bit LDS byte offsets for asm ds_read
    const unsigned base3 =
        (unsigned)(size_t)(__attribute__((address_space(3))) char*)ring;
    const unsigned avv = base3 + jg * 16;          // vector streams base
    const unsigned avs = base3 + 512 + row * 4;    // v scalar base

    asm volatile("s_waitcnt vmcnt(6)" ::: "memory");  // slot0 landed

    Frag FA = {}, FB = {};
    // issue step0 -> FA, step1 -> FB; retire FA
    ISSUE_FRAG(FA, avv, avs);
    ISSUE_FRAG(FB, avv + 1536, avs + 1536);
    TIE_FRAG(FA);

    float S[4] = {0.f, 0.f, 0.f, 0.f};

    for (int p = 0; p < 256; ++p) {
        const int s0 = 2 * p;
        // ---- step 2p on FA (FB's reads in flight) ----
        step_c(S, FA, y, b, h, s0, jg, row);

        if (p & 1)   // next issue crosses into group g+1: gate its DMAs
            asm volatile("s_waitcnt vmcnt(3)" ::: "memory");

        int s2 = s0 + 2; if (s2 > T_ - 1) s2 = T_ - 1;
        unsigned o2 = ((unsigned)((s2 >> 2) & 1)) * 6144 + (unsigned)(s2 & 3) * 1536;
        ISSUE_FRAG(FA, avv + o2, avs + o2);
        TIE_FRAG(FB);

        // ---- step 2p+1 on FB (FA's reads in flight) ----
        step_c(S, FB, y, b, h, s0 + 1, jg, row);

        if (p & 1) {
            // refill slot g&1 with group g+2 (slot's last reads retired above)
            const int g = (s0 + 1) >> 2;
            int gp = g + 2; if (gp > T_ / 4 - 1) gp = T_ / 4 - 1;
            const float* g0 = src + (size_t)gp * 1536 + lane * 4;
            float* l0 = &ring[(g & 1) * 1536];
#pragma unroll
            for (int c = 0; c < 6; ++c)
                gld16(g0 + c * 256, l0 + c * 256);
        }

        int s3 = s0 + 3; if (s3 > T_ - 1) s3 = T_ - 1;
        unsigned o3 = ((unsigned)((s3 >> 2) & 1)) * 6144 + (unsigned)(s3 & 3) * 1536;
        ISSUE_FRAG(FB, avv + o3, avs + o3);
        TIE_FRAG(FA);
    }
}

// ---------------------------------------------------------------------------
// Kernel 3: C[m,o] = scale[o] * sum_d Y[m,d] * Wq[o,d]  (B^T GEMM)
// 128x64 tile, BK=64, 4 waves (2x2 over 64x32 sub-tiles).
// 512 blocks = 2/CU so the co-resident block covers barrier drains.
// ---------------------------------------------------------------------------
__device__ __forceinline__ void gload_lds16(const __hip_bfloat16* g, ushort* l) {
    __builtin_amdgcn_global_load_lds(
        (const __attribute__((address_space(1))) unsigned int*)g,
        (__attribute__((address_space(3))) unsigned int*)l, 16, 0, 0);
}

__global__ __launch_bounds__(256, 2) void gemm_bt(
    const __hip_bfloat16* __restrict__ A,   // [M, K]
    const __hip_bfloat16* __restrict__ Bq,  // [N, K]
    const float* __restrict__ scale,        // [N]
    float* __restrict__ C) {                // [M, N]
    const int K = D_;
    __shared__ __align__(16) ushort As[128 * 64];   // 16 KB
    __shared__ __align__(16) ushort Bs[64 * 64];    //  8 KB

    const int tid = threadIdx.x;
    const int lane = tid & 63;
    const int wave = tid >> 6;
    const int wr = wave >> 1, wc = wave & 1;
    const int m0 = blockIdx.x * 128;
    const int n0 = blockIdx.y * 64;

    const int srow8 = lane >> 3;
    const int scol8 = (lane & 7) * 8;
    const int ml = lane & 15;
    const int kq = (lane >> 4) * 8;

    f32x4 acc[4][2] = {};

    for (int k0 = 0; k0 < K; k0 += 64) {
#pragma unroll
        for (int c = 0; c < 4; ++c) {
            int ra = wave * 32 + c * 8;
            gload_lds16(A + (size_t)(m0 + ra + srow8) * K + k0 + scol8,
                        &As[ra * 64]);
        }
#pragma unroll
        for (int c = 0; c < 2; ++c) {
            int rb = wave * 16 + c * 8;
            gload_lds16(Bq + (size_t)(n0 + rb + srow8) * K + k0 + scol8,
                        &Bs[rb * 64]);
        }
        __syncthreads();
#pragma unroll
        for (int ks = 0; ks < 2; ++ks) {
            short8 af[4], bf[2];
#pragma unroll
            for (int tm = 0; tm < 4; ++tm)
                af[tm] = *(const short8*)(&As[(wr * 64 + tm * 16 + ml) * 64 + ks * 32 + kq]);
#pragma unroll
            for (int tn = 0; tn < 2; ++tn)
                bf[tn] = *(const short8*)(&Bs[(wc * 32 + tn * 16 + ml) * 64 + ks * 32 + kq]);
#pragma unroll
            for (int tm = 0; tm < 4; ++tm)
#pragma unroll
                for (int tn = 0; tn < 2; ++tn)
                    acc[tm][tn] = __builtin_amdgcn_mfma_f32_16x16x32_bf16(
                        af[tm], bf[tn], acc[tm][tn], 0, 0, 0);
        }
        __syncthreads();
    }

#pragma unroll
    for (int tn = 0; tn < 2; ++tn) {
        int gn = n0 + wc * 32 + tn * 16 + ml;
        float sc = scale[gn];
#pragma unroll
        for (int tm = 0; tm < 4; ++tm) {
            int gm = m0 + wr * 64 + tm * 16 + (lane >> 4) * 4;
#pragma unroll
            for (int rg = 0; rg < 4; ++rg)
                C[(size_t)(gm + rg) * D_ + gn] = acc[tm][tn][rg] * sc;
        }
    }
}

// ---------------------------------------------------------------------------
extern "C" void kernel_launch(void* const* d_in, const int* in_sizes, int n_in,
                              void* d_out, int out_size, void* d_ws, size_t ws_size,
                              hipStream_t stream) {
    (void)in_sizes; (void)n_in; (void)out_size; (void)ws_size;
    const float* r  = (const float*)d_in[0];
    const float* w  = (const float*)d_in[1];
    const float* k  = (const float*)d_in[2];
    const float* v  = (const float*)d_in[3];
    const float* ic = (const float*)d_in[4];
    const int*   wq = (const int*)d_in[5];
    const float* sc = (const float*)d_in[6];
    float* out = (float*)d_out;

    // ws: yb 8.4MB | wb 8.4MB | pk (packed streams) 100.7MB  (~118 MB total)
    char* p = (char*)d_ws;
    __hip_bfloat16* yb = (__hip_bfloat16*)p;  p += (size_t)M_ * D_ * 2;
    __hip_bfloat16* wb = (__hip_bfloat16*)p;  p += (size_t)D_ * D_ * 2;
    float* pk = (float*)p;

    prep    <<<dim3(16384), dim3(256), 0, stream>>>(r, w, k, v, ic, pk);
    wkv_scan<<<dim3(2048 + 16384), dim3(64), 0, stream>>>(pk, yb, wq, wb);
    gemm_bt <<<dim3(M_ / 128, D_ / 64), dim3(256), 0, stream>>>(yb, wb, sc, out);
}

// Round 6
// 287.753 us; speedup vs baseline: 1.3029x; 1.0400x over previous
//
#include <hip/hip_runtime.h>
#include <hip/hip_bf16.h>
#include <stdint.h>

#define B_ 4
#define T_ 512
#define H_ 32
#define N_ 64
#define D_ 2048
#define M_ (B_*T_)

typedef __attribute__((ext_vector_type(4))) float f32x4;
typedef __attribute__((ext_vector_type(8))) short short8;

// DPP butterfly add across 16-lane groups: pure VALU.
template <int CTRL>
__device__ __forceinline__ float dpp_add(float x) {
    int t = __builtin_amdgcn_mov_dpp(__float_as_int(x), CTRL, 0xF, 0xF, true);
    return x + __int_as_float(t);
}
__device__ __forceinline__ float bfly16(float x) {
    x = dpp_add<0xB1>(x);    // xor1
    x = dpp_add<0x4E>(x);    // xor2
    x = dpp_add<0x141>(x);   // xor4 row_half_mirror
    x = dpp_add<0x140>(x);   // xor8 row_mirror
    return x;
}

__device__ __forceinline__ void gld16(const float* g, float* l) {
    __builtin_amdgcn_global_load_lds(
        (const __attribute__((address_space(1))) unsigned int*)g,
        (__attribute__((address_space(3))) unsigned int*)l, 16, 0, 0);
}

// ---------------------------------------------------------------------------
// Kernel 1: precompute+pack streams into pk[bh][t][6][64] f32
// (streams: r,k,v,dec,kk,bb) -- exact R2 layout (proven skeleton).
// ---------------------------------------------------------------------------
__global__ __launch_bounds__(256) void prep(
    const float* __restrict__ r, const float* __restrict__ w,
    const float* __restrict__ k, const float* __restrict__ v,
    const float* __restrict__ iclr, float* __restrict__ pk) {
    int g = blockIdx.x * 4 + (threadIdx.x >> 6);   // (b,t,h) flat index
    int lane = threadIdx.x & 63;
    int b = g >> 14;             // / (T*H)
    int t = (g >> 5) & (T_ - 1); // / H % T
    int h = g & 31;              // % H
    size_t si = (size_t)g * 64 + lane;
    size_t di = (((size_t)(b * H_ + h) * T_) + t) * 384 + lane;  // stream 0 chan
    float rv = r[si], wv = w[si], kv = k[si], vv = v[si], av = iclr[si];
    float d = expf(-expf(wv));
    float ss = kv * kv;
#pragma unroll
    for (int m = 1; m < 64; m <<= 1) ss += __shfl_xor(ss, m, 64);
    float kkv = kv * rsqrtf(ss + 1e-12f);
    float bbv = kkv * (1.f / (1.f + expf(-av)));
    pk[di          ] = rv;
    pk[di + 1 * 64 ] = kv;
    pk[di + 2 * 64 ] = vv;
    pk[di + 3 * 64 ] = d;
    pk[di + 4 * 64 ] = kkv;
    pk[di + 5 * 64 ] = bbv;
}

// ---------------------------------------------------------------------------
// Kernel 2: WKV-7 scan, sibling-merged. R5 diagnosis: round-robin dispatch
// put 8 blocks of the SAME bh on each CU -> 8x duplicated DMA (12KB/step/CU
// LDS write-port + 48 VMEM issues/group); aggregate LDS+DMA pipe demand
// (~624 cyc/step/CU) == observed wall (567-638) across R2/R5 variants.
// Now: ONE 512-thread block (8 waves) per (bh, half); ONE shared ring;
// wave 0 is the sole DMA producer (6 DMAs/group). Consumers: pure
// ds_read+compute, no vmem waits. Sync = raw s_barrier pairs (NOT
// __syncthreads: its vmcnt(0) drain would serialize the prefetch).
// wave0 vmcnt ledger: top of group g, queue = [6 DMA g][4 st g-1]
// [6 DMA g+1] -> vmcnt(10) retires exactly data-g. g==0: [6 s0][6 s1]
// -> vmcnt(6). Refill of slot g&1 (data g+2) is issued only after
// barrier2 (all waves done reading slot g&1), so no DMA/ds_read race.
// Blocks >= 256: int32 -> bf16 weight dequant riding in the scan's shadow.
// ---------------------------------------------------------------------------
__global__ __launch_bounds__(512) void wkv_scan(
    const float* __restrict__ pk, __hip_bfloat16* __restrict__ y,
    const int* __restrict__ q, __hip_bfloat16* __restrict__ o) {
    if (blockIdx.x >= 256) {       // ---- weight dequant part ----
        int i = ((blockIdx.x - 256) * 512 + (int)threadIdx.x) * 4;
        int4 qi = *(const int4*)(q + i);
        __hip_bfloat16 t[4];
        t[0] = __float2bfloat16((float)qi.x);
        t[1] = __float2bfloat16((float)qi.y);
        t[2] = __float2bfloat16((float)qi.z);
        t[3] = __float2bfloat16((float)qi.w);
        *(uint2*)(o + i) = *(uint2*)t;
        return;
    }
    const int bh   = blockIdx.x & 127;
    const int half = blockIdx.x >> 7;
    const int tid  = threadIdx.x;
    const int wave = tid >> 6;
    const int lane = tid & 63;
    const int b = bh >> 5, h = bh & 31;
    const int jg = lane & 15;
    const int rl = lane >> 4;
    const int row = (half * 8 + wave) * 4 + rl;

    __shared__ __align__(16) float ring[2 * 1536];   // 12 KB, shared by 8 waves

    const float* src = pk + (size_t)bh * T_ * 384;

    // prologue: producer fills both superslots (12 DMAs outstanding)
    if (wave == 0) {
#pragma unroll
        for (int gg = 0; gg < 2; ++gg)
#pragma unroll
            for (int c = 0; c < 6; ++c)
                gld16(src + gg * 1536 + c * 256 + lane * 4,
                      &ring[gg * 1536 + c * 256]);
    }

    float S[4] = {0.f, 0.f, 0.f, 0.f};

    for (int g = 0; g < T_ / 4; ++g) {
        if (wave == 0) {
            if (g == 0) { asm volatile("s_waitcnt vmcnt(6)"  ::: "memory"); }
            else        { asm volatile("s_waitcnt vmcnt(10)" ::: "memory"); }
        }
        asm volatile("s_barrier" ::: "memory");   // slot g&1 holds data g
        const float* rb0 = &ring[(g & 1) * 1536];

#pragma unroll
        for (int i = 0; i < 4; ++i) {
            const int t = g * 4 + i;
            const float* rb = rb0 + i * 384;

            f32x4 Rc = *(const f32x4*)(rb + 0 * 64 + jg * 4);
            f32x4 Kc = *(const f32x4*)(rb + 1 * 64 + jg * 4);
            float vcv =                 rb[2 * 64 + row];
            f32x4 Dc = *(const f32x4*)(rb + 3 * 64 + jg * 4);
            f32x4 Ac = *(const f32x4*)(rb + 4 * 64 + jg * 4);
            f32x4 Bc = *(const f32x4*)(rb + 5 * 64 + jg * 4);

            // sa = -(S_old . kk)
            float s01 = fmaf(S[1], Ac[1], S[0] * Ac[0]);
            float s23 = fmaf(S[3], Ac[3], S[2] * Ac[2]);
            const float sa = -bfly16(s01 + s23);

            // S = S*dec + sa*bb + v*k ;  y partial = S_new . r
            float t0 = fmaf(sa, Bc[0], vcv * Kc[0]);
            S[0] = fmaf(S[0], Dc[0], t0);
            float t1 = fmaf(sa, Bc[1], vcv * Kc[1]);
            S[1] = fmaf(S[1], Dc[1], t1);
            float y01 = fmaf(S[1], Rc[1], S[0] * Rc[0]);
            float t2 = fmaf(sa, Bc[2], vcv * Kc[2]);
            S[2] = fmaf(S[2], Dc[2], t2);
            float t3 = fmaf(sa, Bc[3], vcv * Kc[3]);
            S[3] = fmaf(S[3], Dc[3], t3);
            float y23 = fmaf(S[3], Rc[3], S[2] * Rc[2]);
            float ys = bfly16(y01 + y23);
            if (jg == 0)
                y[((size_t)b * T_ + t) * D_ + h * 64 + row] = __float2bfloat16(ys);
        }

        asm volatile("s_barrier" ::: "memory");   // all done reading slot g&1

        if (wave == 0) {
            // refill slot g&1 with group g+2 (clamped tail re-reads: harmless)
            int gp = g + 2; if (gp > T_ / 4 - 1) gp = T_ / 4 - 1;
            const float* g0 = src + (size_t)gp * 1536 + lane * 4;
            float* l0 = &ring[(g & 1) * 1536];
#pragma unroll
            for (int c = 0; c < 6; ++c)
                gld16(g0 + c * 256, l0 + c * 256);
        }
    }
}

// ---------------------------------------------------------------------------
// Kernel 3: C[m,o] = scale[o] * sum_d Y[m,d] * Wq[o,d]  (B^T GEMM)
// 128x64 tile, BK=64, 4 waves. R6: TRUE 2-phase prefetch (T3-minimum):
// double-buffered LDS; issue stage(t+1) BEFORE vmcnt(6)+s_barrier for
// tile t, so tile t+1's 6 DMAs fly under tile t's MFMA phase. Raw
// s_barrier (NOT __syncthreads -- its vmcnt(0) drain kills the overlap).
// Per-wave ledger: after issuing stage t+1, queue = [6 t][6 t+1] ->
// vmcnt(6); last tile: vmcnt(0). Slot (t+1)&1 was last read in iter t-1
// and barrier2(t-1) passed before the stage issue -> no write/read race.
// XCD-bijective swizzle (512 = 8 XCD x 64): each XCD owns 4 n-strips
// (1MB of B) -> L2-resident B panels.
// ---------------------------------------------------------------------------
__device__ __forceinline__ void gload_lds16(const __hip_bfloat16* g, ushort* l) {
    __builtin_amdgcn_global_load_lds(
        (const __attribute__((address_space(1))) unsigned int*)g,
        (__attribute__((address_space(3))) unsigned int*)l, 16, 0, 0);
}

__global__ __launch_bounds__(256, 2) void gemm_bt(
    const __hip_bfloat16* __restrict__ A,   // [M, K]
    const __hip_bfloat16* __restrict__ Bq,  // [N, K]
    const float* __restrict__ scale,        // [N]
    float* __restrict__ C) {                // [M, N]
    const int K = D_;
    __shared__ __align__(16) ushort As[2][128 * 64];   // 32 KB
    __shared__ __align__(16) ushort Bs[2][64 * 64];    // 16 KB

    const int tid = threadIdx.x;
    const int lane = tid & 63;
    const int wave = tid >> 6;
    const int wr = wave >> 1, wc = wave & 1;

    // XCD-bijective swizzle: 512 blocks = 8 XCDs x 64 chunks
    const int id = blockIdx.x;
    const int swz = (id & 7) * 64 + (id >> 3);
    const int m0 = (swz & 15) * 128;
    const int n0 = (swz >> 4) * 64;

    const int srow8 = lane >> 3;
    const int scol8 = (lane & 7) * 8;
    const int ml = lane & 15;
    const int kq = (lane >> 4) * 8;

    f32x4 acc[4][2] = {};

#define GSTAGE(slot, kk0)                                                    \
    {                                                                        \
        _Pragma("unroll")                                                    \
        for (int c = 0; c < 4; ++c) {                                        \
            int ra = wave * 32 + c * 8;                                      \
            gload_lds16(A + (size_t)(m0 + ra + srow8) * K + (kk0) + scol8,   \
                        &As[slot][ra * 64]);                                 \
        }                                                                    \
        _Pragma("unroll")                                                    \
        for (int c = 0; c < 2; ++c) {                                        \
            int rb = wave * 16 + c * 8;                                      \
            gload_lds16(Bq + (size_t)(n0 + rb + srow8) * K + (kk0) + scol8,  \
                        &Bs[slot][rb * 64]);                                 \
        }                                                                    \
    }

    GSTAGE(0, 0);                         // prologue: stage tile 0

    for (int t = 0; t < K / 64; ++t) {
        if (t + 1 < K / 64) {
            GSTAGE((t + 1) & 1, (t + 1) * 64);   // issue next tile's DMAs
            asm volatile("s_waitcnt vmcnt(6)" ::: "memory");  // tile t landed
        } else {
            asm volatile("s_waitcnt vmcnt(0)" ::: "memory");
        }
        asm volatile("s_barrier" ::: "memory");
        const int sl = t & 1;
#pragma unroll
        for (int ks = 0; ks < 2; ++ks) {
            short8 af[4], bf[2];
#pragma unroll
            for (int tm = 0; tm < 4; ++tm)
                af[tm] = *(const short8*)(&As[sl][(wr * 64 + tm * 16 + ml) * 64 + ks * 32 + kq]);
#pragma unroll
            for (int tn = 0; tn < 2; ++tn)
                bf[tn] = *(const short8*)(&Bs[sl][(wc * 32 + tn * 16 + ml) * 64 + ks * 32 + kq]);
#pragma unroll
            for (int tm = 0; tm < 4; ++tm)
#pragma unroll
                for (int tn = 0; tn < 2; ++tn)
                    acc[tm][tn] = __builtin_amdgcn_mfma_f32_16x16x32_bf16(
                        af[tm], bf[tn], acc[tm][tn], 0, 0, 0);
        }
        asm volatile("s_barrier" ::: "memory");   // done reading slot sl
    }
#undef GSTAGE

#pragma unroll
    for (int tn = 0; tn < 2; ++tn) {
        int gn = n0 + wc * 32 + tn * 16 + ml;
        float sc = scale[gn];
#pragma unroll
        for (int tm = 0; tm < 4; ++tm) {
            int gm = m0 + wr * 64 + tm * 16 + (lane >> 4) * 4;
#pragma unroll
            for (int rg = 0; rg < 4; ++rg)
                C[(size_t)(gm + rg) * D_ + gn] = acc[tm][tn][rg] * sc;
        }
    }
}

// ---------------------------------------------------------------------------
extern "C" void kernel_launch(void* const* d_in, const int* in_sizes, int n_in,
                              void* d_out, int out_size, void* d_ws, size_t ws_size,
                              hipStream_t stream) {
    (void)in_sizes; (void)n_in; (void)out_size; (void)ws_size;
    const float* r  = (const float*)d_in[0];
    const float* w  = (const float*)d_in[1];
    const float* k  = (const float*)d_in[2];
    const float* v  = (const float*)d_in[3];
    const float* ic = (const float*)d_in[4];
    const int*   wq = (const int*)d_in[5];
    const float* sc = (const float*)d_in[6];
    float* out = (float*)d_out;

    // ws: yb 8.4MB | wb 8.4MB | pk (packed streams) 100.7MB  (~118 MB total)
    char* p = (char*)d_ws;
    __hip_bfloat16* yb = (__hip_bfloat16*)p;  p += (size_t)M_ * D_ * 2;
    __hip_bfloat16* wb = (__hip_bfloat16*)p;  p += (size_t)D_ * D_ * 2;
    float* pk = (float*)p;

    prep    <<<dim3(16384), dim3(256), 0, stream>>>(r, w, k, v, ic, pk);
    wkv_scan<<<dim3(256 + 2048), dim3(512), 0, stream>>>(pk, yb, wq, wb);
    gemm_bt <<<dim3(512), dim3(256), 0, stream>>>(yb, wb, sc, out);
}